// Round 14
// baseline (172.619 us; speedup 1.0000x reference)
//
#include <hip/hip_runtime.h>
#include <math.h>

#define B_SZ 512
#define K_SZ 8
#define L_SZ 50
#define DLLM 768
#define H_SZ 128
#define N_ITEM 100000
#define DIV_TRADEOFF 0.1f
#define M_PAD 100032            // 1563 * 64

typedef float  f32x4 __attribute__((ext_vector_type(4)));
typedef short  bf16x8 __attribute__((ext_vector_type(8)));
typedef unsigned int u32x4 __attribute__((ext_vector_type(4)));
typedef unsigned short u16x8 __attribute__((ext_vector_type(8)));

__device__ __forceinline__ unsigned short f2bf(float f) {   // RNE f32->bf16
    unsigned u = __float_as_uint(f);
    u += 0x7fffu + ((u >> 16) & 1u);
    return (unsigned short)(u >> 16);
}

__device__ __forceinline__ void gload_lds16(const void* g, void* l) {
    __builtin_amdgcn_global_load_lds(
        (const __attribute__((address_space(1))) unsigned*)g,
        (__attribute__((address_space(3))) unsigned*)l, 16, 0, 0);
}

// ---------- Kernel 0: transpose+cast W[768][128]f32 -> Wt[128][768]bf16 -----
__global__ __launch_bounds__(256) void k_wt(
    const float* __restrict__ W,
    unsigned short* __restrict__ Wt,
    float* __restrict__ out)              // also zeroes the scalar output
{
    __shared__ float tile[64][65];
    const int kb = blockIdx.x >> 1;       // 0..11 (k block of 64)
    const int nb = blockIdx.x & 1;        // 0..1  (n block of 64)
    const int t  = threadIdx.x;
    if (blockIdx.x == 0 && t == 0) out[0] = 0.0f;

    const int r  = t >> 2;                // 0..63
    const int c0 = (t & 3) * 16;
    #pragma unroll
    for (int j = 0; j < 4; ++j) {
        const float4 v = *(const float4*)(W + (size_t)(kb * 64 + r) * H_SZ + nb * 64 + c0 + j * 4);
        tile[r][c0 + j * 4 + 0] = v.x;
        tile[r][c0 + j * 4 + 1] = v.y;
        tile[r][c0 + j * 4 + 2] = v.z;
        tile[r][c0 + j * 4 + 3] = v.w;
    }
    __syncthreads();
    const int n  = t >> 2;                // 0..63 output row (n)
    const int k0 = (t & 3) * 16;          // 16 k per thread
    u16x8 lo, hi;
    #pragma unroll
    for (int j = 0; j < 8; ++j) lo[j] = f2bf(tile[k0 + j][n]);
    #pragma unroll
    for (int j = 0; j < 8; ++j) hi[j] = f2bf(tile[k0 + 8 + j][n]);
    unsigned short* dst = Wt + (size_t)(nb * 64 + n) * DLLM + kb * 64 + k0;
    *(u16x8*)(dst)     = lo;
    *(u16x8*)(dst + 8) = hi;
}

// ---------- Kernel 1: projb[M_PAD][128]bf16 = bf16(item) @ bf16(W) ----------
// BARRIER-FREE wave-private pipeline: each wave owns a 16x128 tile with its
// own A (2x2KB f32) + B (2x8KB bf16) LDS double-buffers, staged via
// global_load_lds and retired with counted vmcnt(10). No s_barrier anywhere:
// staging and reading are same-wave, so vmcnt suffices; 8 independent
// waves/CU self-pace. BK=32, 24 chunks. 80 KB LDS -> 2 blocks/CU.
__global__ __launch_bounds__(256) void k_proj(
    const float* __restrict__ item,            // [100001, 768]
    const unsigned short* __restrict__ Wt,     // [128, 768] bf16 (B^T)
    unsigned short* __restrict__ projb)        // [M_PAD, 128] bf16
{
    __shared__ float          As[2][4][16 * 32];   // 2 buf x 4 waves x 2 KB
    __shared__ unsigned short Bs[2][4][128 * 32];  // 2 buf x 4 waves x 8 KB

    const int t    = threadIdx.x;
    const int w    = t >> 6;                   // wave 0..3
    const int lane = t & 63;
    const int nl   = lane & 15;                // A-row / B-col within 16
    const int g    = lane >> 4;                // k-group 0..3
    const int wrow = blockIdx.x * 64 + w * 16; // wave's first global row

    // A stage map: call i (i<2): in-wave row rt = i*8 + (lane>>3), granule lane&7
    const int a_rt = lane >> 3;                // 0..7
    const int a_gr = lane & 7;
    // B stage map: call i (i<8): n-row nt_ = i*16 + (lane>>2), granule lane&3
    const int b_nt = lane >> 2;                // 0..15
    const int b_gr = lane & 3;

    auto STAGE = [&](int d, int c) {           // exactly 10 gload_lds / wave
        const int kc = c * 32;
        #pragma unroll
        for (int i = 0; i < 2; ++i) {          // A: 8 rows x 128B, line-dense
            const int rt = i * 8 + a_rt;
            const int rg = wrow + rt;
            const int rs = (rg <= N_ITEM) ? rg : N_ITEM;
            gload_lds16(item + (size_t)rs * DLLM + kc + (a_gr ^ (rt & 7)) * 4,
                        &As[d][w][i * 256]);
        }
        #pragma unroll
        for (int i = 0; i < 8; ++i) {          // B: 16 rows x 64B
            const int nt_ = i * 16 + b_nt;
            const int kb  = (b_gr ^ ((nt_ ^ (nt_ >> 2)) & 3)) * 8;
            gload_lds16(Wt + (size_t)nt_ * DLLM + kc + kb,
                        &Bs[d][w][i * 512]);
        }
    };

    f32x4 acc[8];
    #pragma unroll
    for (int i = 0; i < 8; ++i) acc[i] = (f32x4){0.f, 0.f, 0.f, 0.f};

    STAGE(0, 0);                               // 10 outstanding

    const int key = nl & 7;
    for (int c = 0; c < 24; ++c) {
        if (c + 1 < 24) {
            STAGE((c + 1) & 1, c + 1);         // 20 outstanding
            asm volatile("s_waitcnt vmcnt(10)" ::: "memory");  // chunk c landed
        } else {
            asm volatile("s_waitcnt vmcnt(0)" ::: "memory");
        }
        __builtin_amdgcn_sched_barrier(0);

        const float*          Ap = &As[c & 1][w][0];
        const unsigned short* Bp = &Bs[c & 1][w][0];

        const f32x4 alo = *(const f32x4*)(Ap + nl * 32 + ((2 * g)     ^ key) * 4);
        const f32x4 ahi = *(const f32x4*)(Ap + nl * 32 + ((2 * g + 1) ^ key) * 4);
        unsigned p0, p1, p2, p3;
        asm("v_cvt_pk_bf16_f32 %0, %1, %2" : "=v"(p0) : "v"(alo.x), "v"(alo.y));
        asm("v_cvt_pk_bf16_f32 %0, %1, %2" : "=v"(p1) : "v"(alo.z), "v"(alo.w));
        asm("v_cvt_pk_bf16_f32 %0, %1, %2" : "=v"(p2) : "v"(ahi.x), "v"(ahi.y));
        asm("v_cvt_pk_bf16_f32 %0, %1, %2" : "=v"(p3) : "v"(ahi.z), "v"(ahi.w));
        union { u32x4 u; bf16x8 s; } af;
        af.u[0] = p0; af.u[1] = p1; af.u[2] = p2; af.u[3] = p3;

        #pragma unroll
        for (int nt = 0; nt < 8; ++nt) {
            const int m  = nt * 16 + nl;
            const int bq = (g ^ ((m ^ (m >> 2)) & 3)) * 8;
            const bf16x8 b = *(const bf16x8*)(Bp + m * 32 + bq);
            acc[nt] = __builtin_amdgcn_mfma_f32_16x16x32_bf16(af.s, b, acc[nt], 0, 0, 0);
        }
    }

    // C/D layout (validated r4-r13): row = wrow + 4*g + rr, col = nt*16 + nl
    const int rbase = wrow + 4 * g;
    #pragma unroll
    for (int nt = 0; nt < 8; ++nt) {
        #pragma unroll
        for (int rr = 0; rr < 4; ++rr) {
            projb[(size_t)(rbase + rr) * H_SZ + nt * 16 + nl] = f2bf(acc[nt][rr]);
        }
    }
}

// ---------- Kernel 2: fused gather + softmax + loss + diversity, per b ------
__global__ __launch_bounds__(512) void k_gloss(
    const int* __restrict__ preds,            // [B,K,L]
    const unsigned short* __restrict__ projb, // [M_PAD,128] bf16
    const float* __restrict__ bproj,          // [128]
    const int* __restrict__ user_id, const float* __restrict__ pref_in,
    const float* __restrict__ pos_label, const float* __restrict__ neg_label,
    const float* __restrict__ user_emb,
    float* __restrict__ out)
{
    const int b    = blockIdx.x;
    const int tid  = threadIdx.x;
    const int wv   = tid >> 6;                // 0..7 = k index
    const int lane = tid & 63;
    const int h2   = lane * 2;

    __shared__ float e[K_SZ][H_SZ + 1];
    __shared__ float pref[H_SZ];
    __shared__ float sdot[K_SZ];
    __shared__ float wg[K_SZ];
    __shared__ float lossb_s;

    {
        const int* __restrict__ p = preds + ((size_t)b * K_SZ + wv) * L_SZ;
        constexpr int PF = 8;
        unsigned buf[PF];
        float wgt[PF];
        #pragma unroll
        for (int i = 0; i < PF; ++i) {
            const int id = p[i];
            const bool v = (id > 0) && (id <= N_ITEM);
            wgt[i] = v ? (1.0f / log2f((float)(i + 2))) : 0.0f;
            buf[i] = *(const unsigned*)(projb + (size_t)(v ? id : 0) * H_SZ + h2);
        }
        float a0 = 0.f, a1 = 0.f;
        #pragma unroll
        for (int l = 0; l < L_SZ; ++l) {
            const int s = l % PF;
            const unsigned u = buf[s];
            const float w = wgt[s];
            if (l + PF < L_SZ) {
                const int id = p[l + PF];
                const bool v = (id > 0) && (id <= N_ITEM);
                wgt[s] = v ? (1.0f / log2f((float)(l + PF + 2))) : 0.0f;
                buf[s] = *(const unsigned*)(projb + (size_t)(v ? id : 0) * H_SZ + h2);
            }
            a0 += w * __uint_as_float(u << 16);
            a1 += w * __uint_as_float(u & 0xffff0000u);
        }
        float sumw = 0.f;
        #pragma unroll
        for (int l = 0; l < L_SZ; ++l) sumw += 1.0f / log2f((float)(l + 2));
        e[wv][h2]     = a0 + bproj[h2]     * sumw;
        e[wv][h2 + 1] = a1 + bproj[h2 + 1] * sumw;
    }
    if (tid < H_SZ) {
        const int uid = user_id[b];
        pref[tid] = pref_in[(size_t)b * H_SZ + tid] + user_emb[(size_t)uid * H_SZ + tid];
    }
    __syncthreads();

    if (tid < 256) {
        const int k = tid >> 5;
        const int l32 = tid & 31;
        float s = e[k][l32] * pref[l32] + e[k][l32 + 32] * pref[l32 + 32]
                + e[k][l32 + 64] * pref[l32 + 64] + e[k][l32 + 96] * pref[l32 + 96];
        #pragma unroll
        for (int m = 16; m >= 1; m >>= 1) s += __shfl_xor(s, m, 64);
        if (l32 == 0) sdot[k] = s;
    }
    __syncthreads();

    if (tid == 0) {
        float mx = sdot[0];
        #pragma unroll
        for (int k = 1; k < K_SZ; ++k) mx = fmaxf(mx, sdot[k]);
        float sum = 0.f; float ex[K_SZ];
        #pragma unroll
        for (int k = 0; k < K_SZ; ++k) { ex[k] = expf(sdot[k] - mx); sum += ex[k]; }
        float ps = 0.f, ns = 0.f;
        #pragma unroll
        for (int k = 0; k < K_SZ; ++k) {
            const float w = ex[k] / sum;
            wg[k] = w;
            ps += pos_label[(size_t)b * K_SZ + k] * w;
            ns += neg_label[(size_t)b * K_SZ + k] * w;
        }
        const float x = ps - ns;
        lossb_s = fmaxf(-x, 0.f) + log1pf(expf(-fabsf(x)));   // softplus(-x)
    }
    __syncthreads();

    if (tid < 64) {
        const int i = tid >> 3;
        const int j = tid & 7;
        float gsum = 0.f;
        for (int h = 0; h < H_SZ; ++h) gsum += e[i][h] * e[j][h];
        float v = (i != j) ? (gsum * gsum * (wg[i] + wg[j])) : 0.f;
        #pragma unroll
        for (int m = 32; m >= 1; m >>= 1) v += __shfl_xor(v, m, 64);
        if (tid == 0) {
            const float mean_div = v / (float)(B_SZ * K_SZ * K_SZ);
            atomicAdd(out, lossb_s + DIV_TRADEOFF * mean_div);
        }
    }
}

// ---------------- Fallback (round-3 verified path) --------------------------
__global__ __launch_bounds__(192) void k_gather_fb(
    const int* __restrict__ preds, const float* __restrict__ item,
    float* __restrict__ wf, float* __restrict__ out)
{
    const int bk  = blockIdx.x;
    const int tid = threadIdx.x;
    if (bk == 0 && tid == 0) out[0] = 0.0f;
    const int* __restrict__ p = preds + (size_t)bk * L_SZ;
    const float* __restrict__ ibase = item + (size_t)tid * 4;
    float4 acc = make_float4(0.f, 0.f, 0.f, 0.f);
    constexpr int PF = 8;
    float4 buf[PF]; float wgt[PF];
    #pragma unroll
    for (int i = 0; i < PF; ++i) {
        const int id = p[i];
        const bool v = (id > 0) && (id <= N_ITEM);
        wgt[i] = v ? (1.0f / log2f((float)(i + 2))) : 0.0f;
        buf[i] = *(const float4*)(ibase + (size_t)(v ? id : 0) * DLLM);
    }
    #pragma unroll
    for (int l = 0; l < L_SZ; ++l) {
        const int s = l % PF;
        const float4 v4 = buf[s];
        const float  w  = wgt[s];
        if (l + PF < L_SZ) {
            const int id = p[l + PF];
            const bool v = (id > 0) && (id <= N_ITEM);
            wgt[s] = v ? (1.0f / log2f((float)(l + PF + 2))) : 0.0f;
            buf[s] = *(const float4*)(ibase + (size_t)(v ? id : 0) * DLLM);
        }
        acc.x += w * v4.x; acc.y += w * v4.y; acc.z += w * v4.z; acc.w += w * v4.w;
    }
    *(float4*)(wf + (size_t)bk * DLLM + (size_t)tid * 4) = acc;
}

__global__ __launch_bounds__(256) void k_projloss_fb(
    const float* __restrict__ wf, const float* __restrict__ W,
    const float* __restrict__ bproj, const int* __restrict__ user_id,
    const float* __restrict__ pref_in, const float* __restrict__ pos_label,
    const float* __restrict__ neg_label, const float* __restrict__ user_emb,
    float* __restrict__ out)
{
    const int b   = blockIdx.x;
    const int tid = threadIdx.x;
    const int c   = tid & (H_SZ - 1);
    const int rg  = tid >> 7;
    __shared__ float A[K_SZ][H_SZ];
    __shared__ float e[K_SZ][H_SZ + 1];
    __shared__ float pref[H_SZ];
    __shared__ float sdot[K_SZ];
    __shared__ float wg[K_SZ];
    __shared__ float lossb_s;
    float acc[4] = {0.f, 0.f, 0.f, 0.f};
    const size_t rowbase = (size_t)b * K_SZ;
    for (int kb = 0; kb < DLLM; kb += H_SZ) {
        __syncthreads();
        {
            const int r  = tid >> 5;
            const int kk = (tid & 31) * 4;
            *(float4*)&A[r][kk] = *(const float4*)(wf + (rowbase + r) * DLLM + kb + kk);
        }
        __syncthreads();
        #pragma unroll 4
        for (int k = 0; k < H_SZ; k += 4) {
            const float4 a0 = *(const float4*)&A[rg][k];
            const float4 a1 = *(const float4*)&A[rg + 2][k];
            const float4 a2 = *(const float4*)&A[rg + 4][k];
            const float4 a3 = *(const float4*)&A[rg + 6][k];
            const float* Wp = W + (size_t)(kb + k) * H_SZ + c;
            const float w0 = Wp[0]; const float w1 = Wp[H_SZ];
            const float w2 = Wp[2 * H_SZ]; const float w3 = Wp[3 * H_SZ];
            acc[0] += a0.x * w0 + a0.y * w1 + a0.z * w2 + a0.w * w3;
            acc[1] += a1.x * w0 + a1.y * w1 + a1.z * w2 + a1.w * w3;
            acc[2] += a2.x * w0 + a2.y * w1 + a2.z * w2 + a2.w * w3;
            acc[3] += a3.x * w0 + a3.y * w1 + a3.z * w2 + a3.w * w3;
        }
    }
    float sumw = 0.f;
    #pragma unroll
    for (int l = 0; l < L_SZ; ++l) sumw += 1.0f / log2f((float)(l + 2));
    const float bterm = bproj[c] * sumw;
    #pragma unroll
    for (int ri = 0; ri < 4; ++ri) e[rg + 2 * ri][c] = acc[ri] + bterm;
    if (tid < H_SZ) {
        const int uid = user_id[b];
        pref[tid] = pref_in[(size_t)b * H_SZ + tid] + user_emb[(size_t)uid * H_SZ + tid];
    }
    __syncthreads();
    {
        const int k    = tid >> 5;
        const int lane = tid & 31;
        float s = e[k][lane] * pref[lane] + e[k][lane + 32] * pref[lane + 32]
                + e[k][lane + 64] * pref[lane + 64] + e[k][lane + 96] * pref[lane + 96];
        #pragma unroll
        for (int m = 16; m >= 1; m >>= 1) s += __shfl_xor(s, m, 64);
        if (lane == 0) sdot[k] = s;
    }
    __syncthreads();
    if (tid == 0) {
        float mx = sdot[0];
        #pragma unroll
        for (int k = 1; k < K_SZ; ++k) mx = fmaxf(mx, sdot[k]);
        float sum = 0.f; float ex[K_SZ];
        #pragma unroll
        for (int k = 0; k < K_SZ; ++k) { ex[k] = expf(sdot[k] - mx); sum += ex[k]; }
        float ps = 0.f, ns = 0.f;
        #pragma unroll
        for (int k = 0; k < K_SZ; ++k) {
            const float w = ex[k] / sum;
            wg[k] = w;
            ps += pos_label[(size_t)b * K_SZ + k] * w;
            ns += neg_label[(size_t)b * K_SZ + k] * w;
        }
        const float x = ps - ns;
        lossb_s = fmaxf(-x, 0.f) + log1pf(expf(-fabsf(x)));
    }
    __syncthreads();
    if (tid < 64) {
        const int i = tid >> 3;
        const int j = tid & 7;
        float g = 0.f;
        for (int h = 0; h < H_SZ; ++h) g += e[i][h] * e[j][h];
        float v = (i != j) ? (g * g * (wg[i] + wg[j])) : 0.f;
        #pragma unroll
        for (int m = 32; m >= 1; m >>= 1) v += __shfl_xor(v, m, 64);
        if (tid == 0) {
            const float mean_div = v / (float)(B_SZ * K_SZ * K_SZ);
            atomicAdd(out, lossb_s + DIV_TRADEOFF * mean_div);
        }
    }
}

extern "C" void kernel_launch(void* const* d_in, const int* in_sizes, int n_in,
                              void* d_out, int out_size, void* d_ws, size_t ws_size,
                              hipStream_t stream) {
    const int*   user_id   = (const int*)  d_in[0];
    const int*   preds     = (const int*)  d_in[1];
    const float* pref_in   = (const float*)d_in[2];
    const float* pos_label = (const float*)d_in[3];
    const float* neg_label = (const float*)d_in[4];
    const float* user_emb  = (const float*)d_in[5];
    const float* item_emb  = (const float*)d_in[6];
    const float* W_proj    = (const float*)d_in[7];
    const float* b_proj    = (const float*)d_in[8];

    float* out = (float*)d_out;

    const size_t projb_bytes = (size_t)M_PAD * H_SZ * sizeof(unsigned short); // 25.6 MB
    const size_t wt_off      = projb_bytes;
    const size_t wt_bytes    = (size_t)H_SZ * DLLM * sizeof(unsigned short);  // 196 KB
    const size_t need        = wt_off + wt_bytes;

    if (ws_size >= need) {
        unsigned short* projb = (unsigned short*)d_ws;
        unsigned short* Wt    = (unsigned short*)((char*)d_ws + wt_off);

        k_wt<<<24, 256, 0, stream>>>(W_proj, Wt, out);
        k_proj<<<M_PAD / 64, 256, 0, stream>>>(item_emb, Wt, projb);
        k_gloss<<<B_SZ, 512, 0, stream>>>(preds, projb, b_proj, user_id, pref_in,
                                          pos_label, neg_label, user_emb, out);
    } else {
        float* wf = (float*)d_ws;   // 12.6 MB (round-3 verified path)
        k_gather_fb<<<B_SZ * K_SZ, 192, 0, stream>>>(preds, item_emb, wf, out);
        k_projloss_fb<<<B_SZ, 256, 0, stream>>>(wf, W_proj, b_proj, user_id, pref_in,
                                                pos_label, neg_label, user_emb, out);
    }
}

// Round 15
// 104.380 us; speedup vs baseline: 1.6538x; 1.6538x over previous
//
#include <hip/hip_runtime.h>
#include <math.h>

#define B_SZ 512
#define K_SZ 8
#define L_SZ 50
#define DLLM 768
#define H_SZ 128
#define N_ITEM 100000
#define DIV_TRADEOFF 0.1f
#define M_PAD 100032            // 1563 * 64

typedef float  f32x4 __attribute__((ext_vector_type(4)));
typedef short  bf16x8 __attribute__((ext_vector_type(8)));
typedef unsigned int u32x4 __attribute__((ext_vector_type(4)));
typedef unsigned short u16x8 __attribute__((ext_vector_type(8)));

__device__ __forceinline__ unsigned short f2bf(float f) {   // RNE f32->bf16
    unsigned u = __float_as_uint(f);
    u += 0x7fffu + ((u >> 16) & 1u);
    return (unsigned short)(u >> 16);
}

__device__ __forceinline__ void gload_lds16(const void* g, void* l) {
    __builtin_amdgcn_global_load_lds(
        (const __attribute__((address_space(1))) unsigned*)g,
        (__attribute__((address_space(3))) unsigned*)l, 16, 0, 0);
}

// ---------- Kernel 0: transpose+cast W[768][128]f32 -> Wt[128][768]bf16 -----
__global__ __launch_bounds__(256) void k_wt(
    const float* __restrict__ W,
    unsigned short* __restrict__ Wt,
    float* __restrict__ out)              // also zeroes the scalar output
{
    __shared__ float tile[64][65];
    const int kb = blockIdx.x >> 1;       // 0..11 (k block of 64)
    const int nb = blockIdx.x & 1;        // 0..1  (n block of 64)
    const int t  = threadIdx.x;
    if (blockIdx.x == 0 && t == 0) out[0] = 0.0f;

    const int r  = t >> 2;                // 0..63
    const int c0 = (t & 3) * 16;
    #pragma unroll
    for (int j = 0; j < 4; ++j) {
        const float4 v = *(const float4*)(W + (size_t)(kb * 64 + r) * H_SZ + nb * 64 + c0 + j * 4);
        tile[r][c0 + j * 4 + 0] = v.x;
        tile[r][c0 + j * 4 + 1] = v.y;
        tile[r][c0 + j * 4 + 2] = v.z;
        tile[r][c0 + j * 4 + 3] = v.w;
    }
    __syncthreads();
    const int n  = t >> 2;                // 0..63 output row (n)
    const int k0 = (t & 3) * 16;          // 16 k per thread
    u16x8 lo, hi;
    #pragma unroll
    for (int j = 0; j < 8; ++j) lo[j] = f2bf(tile[k0 + j][n]);
    #pragma unroll
    for (int j = 0; j < 8; ++j) hi[j] = f2bf(tile[k0 + 8 + j][n]);
    unsigned short* dst = Wt + (size_t)(nb * 64 + n) * DLLM + kb * 64 + k0;
    *(u16x8*)(dst)     = lo;
    *(u16x8*)(dst + 8) = hi;
}

// ---------- Kernel 1: projb[M_PAD][128]bf16 = bf16(item) @ bf16(W) ----------
// r9 verbatim EXCEPT: A (HBM stream) is TRIPLE-buffered and issued 2 chunks
// ahead (covers ~2 chunk-times of HBM latency); B (L2-hot) stays 2-deep at
// distance 1. Counted vmcnt(4) retires exactly {A(c+1),B(c+1)} post-compute,
// keeping A(c+2) in flight. LDS 80 KB -> 2 blocks/CU (same as r9).
__global__ __launch_bounds__(256) void k_proj(
    const float* __restrict__ item,            // [100001, 768]
    const unsigned short* __restrict__ Wt,     // [128, 768] bf16 (B^T)
    unsigned short* __restrict__ projb)        // [M_PAD, 128] bf16
{
    __shared__ float          As[3][64 * 64];  // 3 x 16 KB f32, swizzled granules
    __shared__ unsigned short Bs[2][128 * 64]; // 2 x 16 KB bf16, swizzled granules

    const int t    = threadIdx.x;
    const int brow = blockIdx.x * 64;
    const int w    = t >> 6;                   // wave 0..3
    const int lane = t & 63;
    const int nl   = lane & 15;                // A-row / B-col within 16
    const int g    = lane >> 4;                // k-group 0..3
    const int key  = nl & 7;                   // read-side XOR key

    const int a_rsub = (lane >> 4);            // 0..3
    const int a_gl   = lane & 15;
    const int b_nsub = (lane >> 3);            // 0..7
    const int b_gl   = lane & 7;
    const int b_key  = b_nsub & 7;

    const int r = w * 16 + nl;                 // this lane's A row in tile

    auto STAGE_A = [&](int d, int c) {         // 4 gload_lds / thread
        const int kc = c * 64;
        #pragma unroll
        for (int i = 0; i < 4; ++i) {
            const int row_t = w * 16 + i * 4 + a_rsub;
            const int rowS  = (brow + row_t <= N_ITEM) ? (brow + row_t) : N_ITEM;
            const int ka    = (a_gl ^ (row_t & 7)) * 4;            // swizzled granule
            gload_lds16(item + (size_t)rowS * DLLM + kc + ka,
                        &As[d][w * 1024 + i * 256]);
        }
    };
    auto STAGE_B = [&](int d, int c) {         // 4 gload_lds / thread
        const int kc = c * 64;
        #pragma unroll
        for (int i = 0; i < 4; ++i) {
            const int n_t = w * 32 + i * 8 + b_nsub;
            const int kb  = (b_gl ^ b_key) * 8;                    // swizzled granule
            gload_lds16(Wt + (size_t)n_t * DLLM + kc + kb,
                        &Bs[d][w * 2048 + i * 512]);
        }
    };

    f32x4 acc[8];
    #pragma unroll
    for (int i = 0; i < 8; ++i) acc[i] = (f32x4){0.f, 0.f, 0.f, 0.f};

    // ---- prologue: queue (oldest->newest) = A(0), B(0), A(1)
    STAGE_A(0, 0);
    STAGE_B(0, 0);
    STAGE_A(1, 1);
    asm volatile("s_waitcnt vmcnt(4)" ::: "memory");    // A(0),B(0) landed; A(1) flying
    __builtin_amdgcn_s_barrier();
    __builtin_amdgcn_sched_barrier(0);
    // invariant at top of chunk c: outstanding = A(c+1):4

    for (int c = 0; c < 12; ++c) {
        // issue next-chunk B (distance 1) and next-next A (distance 2)
        if (c + 1 < 12) STAGE_B((c + 1) & 1, c + 1);
        if (c + 2 < 12) STAGE_A((c + 2) % 3, c + 2);
        __builtin_amdgcn_sched_barrier(0);

        const float*          Asc = &As[c % 3][0];
        const unsigned short* Bsc = &Bs[c & 1][0];
        #pragma unroll
        for (int ks = 0; ks < 2; ++ks) {
            const f32x4 alo = *(const f32x4*)&Asc[r * 64 + 4 * ((ks * 8 + 2 * g)     ^ key)];
            const f32x4 ahi = *(const f32x4*)&Asc[r * 64 + 4 * ((ks * 8 + 2 * g + 1) ^ key)];
            unsigned p0, p1, p2, p3;
            asm("v_cvt_pk_bf16_f32 %0, %1, %2" : "=v"(p0) : "v"(alo.x), "v"(alo.y));
            asm("v_cvt_pk_bf16_f32 %0, %1, %2" : "=v"(p1) : "v"(alo.z), "v"(alo.w));
            asm("v_cvt_pk_bf16_f32 %0, %1, %2" : "=v"(p2) : "v"(ahi.x), "v"(ahi.y));
            asm("v_cvt_pk_bf16_f32 %0, %1, %2" : "=v"(p3) : "v"(ahi.z), "v"(ahi.w));
            union { u32x4 u; bf16x8 s; } af;
            af.u[0] = p0; af.u[1] = p1; af.u[2] = p2; af.u[3] = p3;

            #pragma unroll
            for (int nt = 0; nt < 8; ++nt) {
                const bf16x8 b = *(const bf16x8*)&Bsc[(nt * 16 + nl) * 64
                                                      + 8 * ((ks * 4 + g) ^ key)];
                acc[nt] = __builtin_amdgcn_mfma_f32_16x16x32_bf16(af.s, b, acc[nt], 0, 0, 0);
            }
        }

        asm volatile("s_waitcnt lgkmcnt(0)" ::: "memory");   // ds_reads retired
        __builtin_amdgcn_s_barrier();          // readers done (WAR safe for writes)
        __builtin_amdgcn_sched_barrier(0);

        if (c < 10) {
            asm volatile("s_waitcnt vmcnt(4)" ::: "memory"); // A(c+1),B(c+1) landed
            __builtin_amdgcn_s_barrier();      // visible to all waves
            __builtin_amdgcn_sched_barrier(0);
        } else if (c == 10) {
            asm volatile("s_waitcnt vmcnt(0)" ::: "memory"); // drain tail
            __builtin_amdgcn_s_barrier();
            __builtin_amdgcn_sched_barrier(0);
        }
    }

    // C/D layout (validated r4-r14): row = w*16 + 4*g + rr, col = nt*16 + nl
    const int rbase = brow + w * 16 + 4 * g;
    #pragma unroll
    for (int nt = 0; nt < 8; ++nt) {
        #pragma unroll
        for (int rr = 0; rr < 4; ++rr) {
            projb[(size_t)(rbase + rr) * H_SZ + nt * 16 + nl] = f2bf(acc[nt][rr]);
        }
    }
}

// ---------- Kernel 2: fused gather + softmax + loss + diversity, per b ------
__global__ __launch_bounds__(512) void k_gloss(
    const int* __restrict__ preds,            // [B,K,L]
    const unsigned short* __restrict__ projb, // [M_PAD,128] bf16
    const float* __restrict__ bproj,          // [128]
    const int* __restrict__ user_id, const float* __restrict__ pref_in,
    const float* __restrict__ pos_label, const float* __restrict__ neg_label,
    const float* __restrict__ user_emb,
    float* __restrict__ out)
{
    const int b    = blockIdx.x;
    const int tid  = threadIdx.x;
    const int wv   = tid >> 6;                // 0..7 = k index
    const int lane = tid & 63;
    const int h2   = lane * 2;

    __shared__ float e[K_SZ][H_SZ + 1];
    __shared__ float pref[H_SZ];
    __shared__ float sdot[K_SZ];
    __shared__ float wg[K_SZ];
    __shared__ float lossb_s;

    {
        const int* __restrict__ p = preds + ((size_t)b * K_SZ + wv) * L_SZ;
        constexpr int PF = 8;
        unsigned buf[PF];
        float wgt[PF];
        #pragma unroll
        for (int i = 0; i < PF; ++i) {
            const int id = p[i];
            const bool v = (id > 0) && (id <= N_ITEM);
            wgt[i] = v ? (1.0f / log2f((float)(i + 2))) : 0.0f;
            buf[i] = *(const unsigned*)(projb + (size_t)(v ? id : 0) * H_SZ + h2);
        }
        float a0 = 0.f, a1 = 0.f;
        #pragma unroll
        for (int l = 0; l < L_SZ; ++l) {
            const int s = l % PF;
            const unsigned u = buf[s];
            const float w = wgt[s];
            if (l + PF < L_SZ) {
                const int id = p[l + PF];
                const bool v = (id > 0) && (id <= N_ITEM);
                wgt[s] = v ? (1.0f / log2f((float)(l + PF + 2))) : 0.0f;
                buf[s] = *(const unsigned*)(projb + (size_t)(v ? id : 0) * H_SZ + h2);
            }
            a0 += w * __uint_as_float(u << 16);
            a1 += w * __uint_as_float(u & 0xffff0000u);
        }
        float sumw = 0.f;
        #pragma unroll
        for (int l = 0; l < L_SZ; ++l) sumw += 1.0f / log2f((float)(l + 2));
        e[wv][h2]     = a0 + bproj[h2]     * sumw;
        e[wv][h2 + 1] = a1 + bproj[h2 + 1] * sumw;
    }
    if (tid < H_SZ) {
        const int uid = user_id[b];
        pref[tid] = pref_in[(size_t)b * H_SZ + tid] + user_emb[(size_t)uid * H_SZ + tid];
    }
    __syncthreads();

    if (tid < 256) {
        const int k = tid >> 5;
        const int l32 = tid & 31;
        float s = e[k][l32] * pref[l32] + e[k][l32 + 32] * pref[l32 + 32]
                + e[k][l32 + 64] * pref[l32 + 64] + e[k][l32 + 96] * pref[l32 + 96];
        #pragma unroll
        for (int m = 16; m >= 1; m >>= 1) s += __shfl_xor(s, m, 64);
        if (l32 == 0) sdot[k] = s;
    }
    __syncthreads();

    if (tid == 0) {
        float mx = sdot[0];
        #pragma unroll
        for (int k = 1; k < K_SZ; ++k) mx = fmaxf(mx, sdot[k]);
        float sum = 0.f; float ex[K_SZ];
        #pragma unroll
        for (int k = 0; k < K_SZ; ++k) { ex[k] = expf(sdot[k] - mx); sum += ex[k]; }
        float ps = 0.f, ns = 0.f;
        #pragma unroll
        for (int k = 0; k < K_SZ; ++k) {
            const float w = ex[k] / sum;
            wg[k] = w;
            ps += pos_label[(size_t)b * K_SZ + k] * w;
            ns += neg_label[(size_t)b * K_SZ + k] * w;
        }
        const float x = ps - ns;
        lossb_s = fmaxf(-x, 0.f) + log1pf(expf(-fabsf(x)));   // softplus(-x)
    }
    __syncthreads();

    if (tid < 64) {
        const int i = tid >> 3;
        const int j = tid & 7;
        float gsum = 0.f;
        for (int h = 0; h < H_SZ; ++h) gsum += e[i][h] * e[j][h];
        float v = (i != j) ? (gsum * gsum * (wg[i] + wg[j])) : 0.f;
        #pragma unroll
        for (int m = 32; m >= 1; m >>= 1) v += __shfl_xor(v, m, 64);
        if (tid == 0) {
            const float mean_div = v / (float)(B_SZ * K_SZ * K_SZ);
            atomicAdd(out, lossb_s + DIV_TRADEOFF * mean_div);
        }
    }
}

// ---------------- Fallback (round-3 verified path) --------------------------
__global__ __launch_bounds__(192) void k_gather_fb(
    const int* __restrict__ preds, const float* __restrict__ item,
    float* __restrict__ wf, float* __restrict__ out)
{
    const int bk  = blockIdx.x;
    const int tid = threadIdx.x;
    if (bk == 0 && tid == 0) out[0] = 0.0f;
    const int* __restrict__ p = preds + (size_t)bk * L_SZ;
    const float* __restrict__ ibase = item + (size_t)tid * 4;
    float4 acc = make_float4(0.f, 0.f, 0.f, 0.f);
    constexpr int PF = 8;
    float4 buf[PF]; float wgt[PF];
    #pragma unroll
    for (int i = 0; i < PF; ++i) {
        const int id = p[i];
        const bool v = (id > 0) && (id <= N_ITEM);
        wgt[i] = v ? (1.0f / log2f((float)(i + 2))) : 0.0f;
        buf[i] = *(const float4*)(ibase + (size_t)(v ? id : 0) * DLLM);
    }
    #pragma unroll
    for (int l = 0; l < L_SZ; ++l) {
        const int s = l % PF;
        const float4 v4 = buf[s];
        const float  w  = wgt[s];
        if (l + PF < L_SZ) {
            const int id = p[l + PF];
            const bool v = (id > 0) && (id <= N_ITEM);
            wgt[s] = v ? (1.0f / log2f((float)(l + PF + 2))) : 0.0f;
            buf[s] = *(const float4*)(ibase + (size_t)(v ? id : 0) * DLLM);
        }
        acc.x += w * v4.x; acc.y += w * v4.y; acc.z += w * v4.z; acc.w += w * v4.w;
    }
    *(float4*)(wf + (size_t)bk * DLLM + (size_t)tid * 4) = acc;
}

__global__ __launch_bounds__(256) void k_projloss_fb(
    const float* __restrict__ wf, const float* __restrict__ W,
    const float* __restrict__ bproj, const int* __restrict__ user_id,
    const float* __restrict__ pref_in, const float* __restrict__ pos_label,
    const float* __restrict__ neg_label, const float* __restrict__ user_emb,
    float* __restrict__ out)
{
    const int b   = blockIdx.x;
    const int tid = threadIdx.x;
    const int c   = tid & (H_SZ - 1);
    const int rg  = tid >> 7;
    __shared__ float A[K_SZ][H_SZ];
    __shared__ float e[K_SZ][H_SZ + 1];
    __shared__ float pref[H_SZ];
    __shared__ float sdot[K_SZ];
    __shared__ float wg[K_SZ];
    __shared__ float lossb_s;
    float acc[4] = {0.f, 0.f, 0.f, 0.f};
    const size_t rowbase = (size_t)b * K_SZ;
    for (int kb = 0; kb < DLLM; kb += H_SZ) {
        __syncthreads();
        {
            const int r  = tid >> 5;
            const int kk = (tid & 31) * 4;
            *(float4*)&A[r][kk] = *(const float4*)(wf + (rowbase + r) * DLLM + kb + kk);
        }
        __syncthreads();
        #pragma unroll 4
        for (int k = 0; k < H_SZ; k += 4) {
            const float4 a0 = *(const float4*)&A[rg][k];
            const float4 a1 = *(const float4*)&A[rg + 2][k];
            const float4 a2 = *(const float4*)&A[rg + 4][k];
            const float4 a3 = *(const float4*)&A[rg + 6][k];
            const float* Wp = W + (size_t)(kb + k) * H_SZ + c;
            const float w0 = Wp[0]; const float w1 = Wp[H_SZ];
            const float w2 = Wp[2 * H_SZ]; const float w3 = Wp[3 * H_SZ];
            acc[0] += a0.x * w0 + a0.y * w1 + a0.z * w2 + a0.w * w3;
            acc[1] += a1.x * w0 + a1.y * w1 + a1.z * w2 + a1.w * w3;
            acc[2] += a2.x * w0 + a2.y * w1 + a2.z * w2 + a2.w * w3;
            acc[3] += a3.x * w0 + a3.y * w1 + a3.z * w2 + a3.w * w3;
        }
    }
    float sumw = 0.f;
    #pragma unroll
    for (int l = 0; l < L_SZ; ++l) sumw += 1.0f / log2f((float)(l + 2));
    const float bterm = bproj[c] * sumw;
    #pragma unroll
    for (int ri = 0; ri < 4; ++ri) e[rg + 2 * ri][c] = acc[ri] + bterm;
    if (tid < H_SZ) {
        const int uid = user_id[b];
        pref[tid] = pref_in[(size_t)b * H_SZ + tid] + user_emb[(size_t)uid * H_SZ + tid];
    }
    __syncthreads();
    {
        const int k    = tid >> 5;
        const int lane = tid & 31;
        float s = e[k][lane] * pref[lane] + e[k][lane + 32] * pref[lane + 32]
                + e[k][lane + 64] * pref[lane + 64] + e[k][lane + 96] * pref[lane + 96];
        #pragma unroll
        for (int m = 16; m >= 1; m >>= 1) s += __shfl_xor(s, m, 64);
        if (lane == 0) sdot[k] = s;
    }
    __syncthreads();
    if (tid == 0) {
        float mx = sdot[0];
        #pragma unroll
        for (int k = 1; k < K_SZ; ++k) mx = fmaxf(mx, sdot[k]);
        float sum = 0.f; float ex[K_SZ];
        #pragma unroll
        for (int k = 0; k < K_SZ; ++k) { ex[k] = expf(sdot[k] - mx); sum += ex[k]; }
        float ps = 0.f, ns = 0.f;
        #pragma unroll
        for (int k = 0; k < K_SZ; ++k) {
            const float w = ex[k] / sum;
            wg[k] = w;
            ps += pos_label[(size_t)b * K_SZ + k] * w;
            ns += neg_label[(size_t)b * K_SZ + k] * w;
        }
        const float x = ps - ns;
        lossb_s = fmaxf(-x, 0.f) + log1pf(expf(-fabsf(x)));
    }
    __syncthreads();
    if (tid < 64) {
        const int i = tid >> 3;
        const int j = tid & 7;
        float g = 0.f;
        for (int h = 0; h < H_SZ; ++h) g += e[i][h] * e[j][h];
        float v = (i != j) ? (g * g * (wg[i] + wg[j])) : 0.f;
        #pragma unroll
        for (int m = 32; m >= 1; m >>= 1) v += __shfl_xor(v, m, 64);
        if (tid == 0) {
            const float mean_div = v / (float)(B_SZ * K_SZ * K_SZ);
            atomicAdd(out, lossb_s + DIV_TRADEOFF * mean_div);
        }
    }
}

extern "C" void kernel_launch(void* const* d_in, const int* in_sizes, int n_in,
                              void* d_out, int out_size, void* d_ws, size_t ws_size,
                              hipStream_t stream) {
    const int*   user_id   = (const int*)  d_in[0];
    const int*   preds     = (const int*)  d_in[1];
    const float* pref_in   = (const float*)d_in[2];
    const float* pos_label = (const float*)d_in[3];
    const float* neg_label = (const float*)d_in[4];
    const float* user_emb  = (const float*)d_in[5];
    const float* item_emb  = (const float*)d_in[6];
    const float* W_proj    = (const float*)d_in[7];
    const float* b_proj    = (const float*)d_in[8];

    float* out = (float*)d_out;

    const size_t projb_bytes = (size_t)M_PAD * H_SZ * sizeof(unsigned short); // 25.6 MB
    const size_t wt_off      = projb_bytes;
    const size_t wt_bytes    = (size_t)H_SZ * DLLM * sizeof(unsigned short);  // 196 KB
    const size_t need        = wt_off + wt_bytes;

    if (ws_size >= need) {
        unsigned short* projb = (unsigned short*)d_ws;
        unsigned short* Wt    = (unsigned short*)((char*)d_ws + wt_off);

        k_wt<<<24, 256, 0, stream>>>(W_proj, Wt, out);
        k_proj<<<M_PAD / 64, 256, 0, stream>>>(item_emb, Wt, projb);
        k_gloss<<<B_SZ, 512, 0, stream>>>(preds, projb, b_proj, user_id, pref_in,
                                          pos_label, neg_label, user_emb, out);
    } else {
        float* wf = (float*)d_ws;   // 12.6 MB (round-3 verified path)
        k_gather_fb<<<B_SZ * K_SZ, 192, 0, stream>>>(preds, item_emb, wf, out);
        k_projloss_fb<<<B_SZ, 256, 0, stream>>>(wf, W_proj, b_proj, user_id, pref_in,
                                                pos_label, neg_label, user_emb, out);
    }
}